// Round 1
// baseline (359.143 us; speedup 1.0000x reference)
//
#include <hip/hip_runtime.h>
#include <math.h>

// TripletLoss fused kernel, round 0: fp32 tiled Gram + streaming per-row stats.
//
// Reference reduction per row i over all j:
//   d2 = sq_i + sq_j - 2*dot(x_i,x_j); dsq = max(d2, 1e-12)   [== dist^2 up to 1 ulp]
//   positives (t_i==t_j, incl. self): drop the min element (== self, dist~1e-6)
//     sigma_p = (sum_p - min_p)/(cnt_p-1); dist_ap = max_p/sigma_p + 0.5*log(sigma_p)
//     (max over pos\{min} == max over pos whenever cnt_p>=2)
//   negatives: sigma_n = sum_n/cnt_n; dist_an = min_n/sigma_n + 0.5*log(sigma_n)
//   loss = mean(max(0, dist_ap - dist_an + 0.3))

#define NROWS 8192
#define DDIM  128
#define BM 64
#define BN 64
#define LSTRIDE 68          // 64 + 4 pad: A reads conflict-free, B reads 2-way (free)
#define TILES_J (NROWS / BN)   // 128
#define LOSS_MARGIN 0.3f

__global__ __launch_bounds__(256) void sq_kernel(const float* __restrict__ X,
                                                 float* __restrict__ sq) {
    int row  = blockIdx.x * 4 + (threadIdx.x >> 6);
    int lane = threadIdx.x & 63;
    const float2* p = (const float2*)(X + (size_t)row * DDIM);
    float2 v = p[lane];                       // 2 floats/lane * 64 lanes = 128
    float s = v.x * v.x + v.y * v.y;
    for (int d = 32; d > 0; d >>= 1) s += __shfl_down(s, d, 64);
    if (lane == 0) sq[row] = s;
}

__global__ __launch_bounds__(256) void dist_kernel(const float* __restrict__ X,
                                                   const int* __restrict__ tgt,
                                                   const float* __restrict__ sq,
                                                   float* __restrict__ partial,
                                                   int tilesPerSlice) {
    __shared__ float As[2][BM * LSTRIDE];   // K chunks of 64
    __shared__ float Bs[BN * LSTRIDE];      // one K chunk at a time
    __shared__ float sqB[BN];
    __shared__ int   tgB[BN];

    const int tid = threadIdx.x;
    const int tx = tid & 15;        // column group: cols tx + 16*c
    const int ty = tid >> 4;        // row group:    rows ty + 16*r
    const int i0 = blockIdx.x * BM;
    const int slice = blockIdx.y;

    // ---- stage A rows (both K chunks) into LDS, coalesced float4 ----
    #pragma unroll
    for (int s = 0; s < 8; ++s) {
        int f = s * 256 + tid;              // 0..2047 = 64 rows * 32 float4
        int row = f >> 5;
        int c4  = f & 31;
        float4 v = ((const float4*)(X + (size_t)(i0 + row) * DDIM))[c4];
        int ch = c4 >> 4;
        int kk = (c4 & 15) * 4;
        *(float4*)&As[ch][row * LSTRIDE + kk] = v;
    }

    float sqA[4]; int tgA[4];
    #pragma unroll
    for (int r = 0; r < 4; ++r) {
        int gi = i0 + ty + 16 * r;
        sqA[r] = sq[gi];
        tgA[r] = tgt[gi];
    }

    float sum_p[4] = {0.f,0.f,0.f,0.f};
    float cnt_p[4] = {0.f,0.f,0.f,0.f};
    float max_p[4] = {-INFINITY,-INFINITY,-INFINITY,-INFINITY};
    float min_p[4] = { INFINITY, INFINITY, INFINITY, INFINITY};
    float sum_n[4] = {0.f,0.f,0.f,0.f};
    float min_n[4] = { INFINITY, INFINITY, INFINITY, INFINITY};

    for (int t = 0; t < tilesPerSlice; ++t) {
        const int j0 = (slice * tilesPerSlice + t) * BN;
        float acc[4][4] = {};

        __syncthreads();   // previous iteration done with sqB/tgB/Bs
        if (tid < BN) { sqB[tid] = sq[j0 + tid]; tgB[tid] = tgt[j0 + tid]; }

        #pragma unroll
        for (int ch = 0; ch < 2; ++ch) {
            // stage B chunk (64 rows x 64 floats), coalesced
            #pragma unroll
            for (int s = 0; s < 4; ++s) {
                int f = s * 256 + tid;          // 0..1023 = 64 rows * 16 float4
                int row = f >> 4;
                int c4  = f & 15;
                float4 v = ((const float4*)(X + (size_t)(j0 + row) * DDIM))[(ch << 4) + c4];
                *(float4*)&Bs[row * LSTRIDE + c4 * 4] = v;
            }
            __syncthreads();

            #pragma unroll 4
            for (int kk = 0; kk < 64; kk += 4) {
                float4 a4[4], b4[4];
                #pragma unroll
                for (int r = 0; r < 4; ++r)
                    a4[r] = *(const float4*)&As[ch][(ty + 16 * r) * LSTRIDE + kk];
                #pragma unroll
                for (int c = 0; c < 4; ++c)
                    b4[c] = *(const float4*)&Bs[(tx + 16 * c) * LSTRIDE + kk];
                #pragma unroll
                for (int r = 0; r < 4; ++r)
                    #pragma unroll
                    for (int c = 0; c < 4; ++c) {
                        acc[r][c] = fmaf(a4[r].x, b4[c].x, acc[r][c]);
                        acc[r][c] = fmaf(a4[r].y, b4[c].y, acc[r][c]);
                        acc[r][c] = fmaf(a4[r].z, b4[c].z, acc[r][c]);
                        acc[r][c] = fmaf(a4[r].w, b4[c].w, acc[r][c]);
                    }
            }
            __syncthreads();   // before overwriting Bs with next chunk / next tile
        }

        // ---- fused epilogue: streaming stats ----
        #pragma unroll
        for (int c = 0; c < 4; ++c) {
            int jl = tx + 16 * c;
            float sqj = sqB[jl];
            int   tj  = tgB[jl];
            #pragma unroll
            for (int r = 0; r < 4; ++r) {
                float d2  = fmaf(-2.0f, acc[r][c], sqA[r] + sqj);
                float dsq = fmaxf(d2, 1e-12f);
                bool same = (tgA[r] == tj);
                sum_p[r] += same ? dsq : 0.0f;
                cnt_p[r] += same ? 1.0f : 0.0f;
                max_p[r]  = same ? fmaxf(max_p[r], dsq) : max_p[r];
                min_p[r]  = same ? fminf(min_p[r], dsq) : min_p[r];
                sum_n[r] += same ? 0.0f : dsq;
                min_n[r]  = same ? min_n[r] : fminf(min_n[r], dsq);
            }
        }
    }

    // ---- reduce across the 16 tx threads sharing each row ----
    #pragma unroll
    for (int r = 0; r < 4; ++r) {
        for (int d = 8; d > 0; d >>= 1) {
            sum_p[r] += __shfl_down(sum_p[r], d, 16);
            cnt_p[r] += __shfl_down(cnt_p[r], d, 16);
            max_p[r]  = fmaxf(max_p[r], __shfl_down(max_p[r], d, 16));
            min_p[r]  = fminf(min_p[r], __shfl_down(min_p[r], d, 16));
            sum_n[r] += __shfl_down(sum_n[r], d, 16);
            min_n[r]  = fminf(min_n[r], __shfl_down(min_n[r], d, 16));
        }
        if (tx == 0) {
            int gi = i0 + ty + 16 * r;
            float* p = partial + ((size_t)slice * NROWS + gi) * 6;
            p[0] = sum_p[r]; p[1] = cnt_p[r]; p[2] = max_p[r];
            p[3] = min_p[r]; p[4] = sum_n[r]; p[5] = min_n[r];
        }
    }
}

__global__ __launch_bounds__(256) void combine_kernel(const float* __restrict__ partial,
                                                      float* __restrict__ out,
                                                      int nSlices) {
    int row = blockIdx.x * 256 + threadIdx.x;
    float sum_p = 0.f, cnt_p = 0.f, max_p = -INFINITY, min_p = INFINITY;
    float sum_n = 0.f, min_n = INFINITY;
    for (int g = 0; g < nSlices; ++g) {
        const float* p = partial + ((size_t)g * NROWS + row) * 6;
        sum_p += p[0]; cnt_p += p[1];
        max_p = fmaxf(max_p, p[2]); min_p = fminf(min_p, p[3]);
        sum_n += p[4]; min_n = fminf(min_n, p[5]);
    }
    float sigma_p  = (sum_p - min_p) / (cnt_p - 1.0f);
    float dist_ap  = max_p / sigma_p + 0.5f * logf(sigma_p);
    float cnt_n    = (float)NROWS - cnt_p;
    float sigma_n  = sum_n / cnt_n;
    float dist_an  = min_n / sigma_n + 0.5f * logf(sigma_n);
    float h = fmaxf(dist_ap - dist_an + LOSS_MARGIN, 0.0f);

    for (int d = 32; d > 0; d >>= 1) h += __shfl_down(h, d, 64);
    __shared__ float wsum[4];
    int lane = threadIdx.x & 63, w = threadIdx.x >> 6;
    if (lane == 0) wsum[w] = h;
    __syncthreads();
    if (threadIdx.x == 0)
        atomicAdd(out, (wsum[0] + wsum[1] + wsum[2] + wsum[3]) * (1.0f / NROWS));
}

extern "C" void kernel_launch(void* const* d_in, const int* in_sizes, int n_in,
                              void* d_out, int out_size, void* d_ws, size_t ws_size,
                              hipStream_t stream) {
    const float* X   = (const float*)d_in[0];
    const int*   tgt = (const int*)d_in[1];
    float* out = (float*)d_out;

    // workspace layout: sq[N] | partial[G][N][6]
    float* sq = (float*)d_ws;
    float* partial = sq + NROWS;

    int G = 4;
    while (G > 1 && ws_size < ((size_t)NROWS + (size_t)G * NROWS * 6) * sizeof(float))
        G >>= 1;
    int tilesPerSlice = TILES_J / G;

    hipMemsetAsync(out, 0, sizeof(float), stream);
    sq_kernel<<<NROWS / 4, 256, 0, stream>>>(X, sq);
    dist_kernel<<<dim3(NROWS / BM, G), 256, 0, stream>>>(X, tgt, sq, partial, tilesPerSlice);
    combine_kernel<<<NROWS / 256, 256, 0, stream>>>(partial, out, G);
}

// Round 2
// 199.605 us; speedup vs baseline: 1.7993x; 1.7993x over previous
//
#include <hip/hip_runtime.h>
#include <math.h>

// TripletLoss round 2: bf16 MFMA Gram + per-COLUMN streaming stats (exact by symmetry).
//
// Per column j (== per row i by exact symmetry of the computed Gram):
//   d2_ij = sq_i + sq_j - 2*acc_ij = 2*(u_i + u_j - acc),  u = sq/2
//   sum_all = S_all + N*sq_j - 2*Sum(acc)         (S_all = sum_i sq_i, precomputed)
//   sum_p   = S_class[t_j] + cnt*sq_j - 2*Sum_same(acc)
//   max_p d2 = sq_j + 2*max_same(u_i - acc);  min_n d2 = sq_j + 2*min_diff(u_i - acc)
//   self d2 (the dropped min positive) = sq_j + 2*(u_j - acc_jj), diagonal tile only.
// u_i carries the class tag in its low 8 mantissa bits (<=0.002 perturbation, harmless).

#define NROWS 8192
#define DDIM 128
#define MARGIN_F 0.3f

typedef short bf16x8 __attribute__((ext_vector_type(8)));
typedef float f32x16 __attribute__((ext_vector_type(16)));

union U4B { uint4 u; bf16x8 h; };

__device__ __forceinline__ unsigned f2bf(float x) {
    unsigned u = __float_as_uint(x);
    return (u + 0x7fffu + ((u >> 16) & 1u)) >> 16;
}

// ---- prep: sq, packed u+tag, bf16 copy of X, class tables ----
__global__ __launch_bounds__(256) void prep_kernel(const float* __restrict__ X,
                                                   const int* __restrict__ tgt,
                                                   float* __restrict__ sq,
                                                   float* __restrict__ upk,
                                                   unsigned short* __restrict__ Xbf,
                                                   float* __restrict__ S_class,
                                                   int* __restrict__ hist) {
    int w = threadIdx.x >> 6, l = threadIdx.x & 63;
    int row = blockIdx.x * 4 + w;
    float2 v = ((const float2*)(X + (size_t)row * DDIM))[l];
    // bf16 store (RNE)
    ushort2 h; h.x = (unsigned short)f2bf(v.x); h.y = (unsigned short)f2bf(v.y);
    ((ushort2*)(Xbf + (size_t)row * DDIM))[l] = h;
    float s = v.x * v.x + v.y * v.y;
    for (int d = 32; d > 0; d >>= 1) s += __shfl_down(s, d, 64);
    if (l == 0) {
        int t = tgt[row];
        sq[row] = s;
        unsigned ui = (__float_as_uint(0.5f * s) & 0xffffff00u) | (unsigned)t;
        upk[row] = __uint_as_float(ui);
        atomicAdd(&S_class[t], s);
        atomicAdd(&hist[t], 1);
    }
}

// ---- main: bf16 MFMA Gram with fused column-stats ----
__global__ __launch_bounds__(256, 2) void dist_kernel(const unsigned short* __restrict__ Xbf,
                                                      const int* __restrict__ tgt,
                                                      const float* __restrict__ upk,
                                                      float* __restrict__ partial,
                                                      int tps) {
    __shared__ uint4 As[128 * 16];   // 128 rows x 16 chunks (16B), XOR-swizzled

    const int tid = threadIdx.x;
    const int w = tid >> 6;          // wave id: rows w*32..w*32+31 of each i-tile
    const int l = tid & 63;
    const int hl = l >> 5;
    const int l31 = l & 31;
    const int jb = blockIdx.x;       // column block: cols jb*128..+127
    const int slice = blockIdx.y;

    // ---- B fragments: the block's 128 columns, full K=128, in registers ----
    bf16x8 Bf[4][8];
    int tjt[4];
    #pragma unroll
    for (int ct = 0; ct < 4; ++ct) {
        int col = jb * 128 + ct * 32 + l31;
        tjt[ct] = tgt[col];
        const uint4* src = (const uint4*)Xbf + (size_t)col * 16;
        #pragma unroll
        for (int kk = 0; kk < 8; ++kk) {
            U4B t; t.u = src[kk * 2 + hl];
            Bf[ct][kk] = t.h;
        }
    }

    float Sa[4]  = {0.f, 0.f, 0.f, 0.f};
    float Sas[4] = {0.f, 0.f, 0.f, 0.f};
    float Mp[4]  = {-INFINITY, -INFINITY, -INFINITY, -INFINITY};
    float Mn[4]  = { INFINITY,  INFINITY,  INFINITY,  INFINITY};
    float selfv  =  INFINITY;

    for (int t = 0; t < tps; ++t) {
        const int i0 = (slice * tps + t) * 128;

        __syncthreads();
        #pragma unroll
        for (int s = 0; s < 8; ++s) {
            int g = s * 256 + tid;       // 2048 chunks = 128 rows x 16
            int row = g >> 4, c = g & 15;
            As[row * 16 + (c ^ (row & 15))] =
                ((const uint4*)Xbf)[(size_t)(i0 + row) * 16 + c];
        }
        __syncthreads();

        // row data (u_i with tag) for this wave's 32 rows, reg-mapped
        float urow[16];
        #pragma unroll
        for (int r = 0; r < 16; ++r) {
            int base = (r & 3) + 8 * (r >> 2);
            urow[r] = upk[i0 + w * 32 + base + 4 * hl];
        }

        f32x16 acc[4];
        #pragma unroll
        for (int ct = 0; ct < 4; ++ct) acc[ct] = (f32x16)0.0f;

        const int arow = w * 32 + l31;
        #pragma unroll
        for (int kk = 0; kk < 8; ++kk) {
            U4B a; a.u = As[arow * 16 + ((kk * 2 + hl) ^ (l & 15))];
            #pragma unroll
            for (int ct = 0; ct < 4; ++ct)
                acc[ct] = __builtin_amdgcn_mfma_f32_32x32x16_bf16(a.h, Bf[ct][kk], acc[ct], 0, 0, 0);
        }

        const bool diag = (i0 == jb * 128);
        #pragma unroll
        for (int ct = 0; ct < 4; ++ct) {
            const int tt = tjt[ct];
            #pragma unroll
            for (int r = 0; r < 16; ++r) {
                float a = acc[ct][r];
                float v = urow[r] - a;
                bool same = ((__float_as_int(urow[r]) & 0xff) == tt);
                Sa[ct] += a;
                Sas[ct] += same ? a : 0.0f;
                Mp[ct] = fmaxf(Mp[ct], same ? v : -INFINITY);
                Mn[ct] = fminf(Mn[ct], same ? INFINITY : v);
            }
            if (diag && ct == w) {
                #pragma unroll
                for (int r = 0; r < 16; ++r) {
                    int rowl = (r & 3) + 8 * (r >> 2) + 4 * hl;
                    if (rowl == l31) selfv = urow[r] - acc[ct][r];
                }
            }
        }
    }

    // combine the two half-lanes (same columns, complementary rows)
    #pragma unroll
    for (int ct = 0; ct < 4; ++ct) {
        Sa[ct]  += __shfl_xor(Sa[ct], 32);
        Sas[ct] += __shfl_xor(Sas[ct], 32);
        Mp[ct]   = fmaxf(Mp[ct], __shfl_xor(Mp[ct], 32));
        Mn[ct]   = fminf(Mn[ct], __shfl_xor(Mn[ct], 32));
    }
    selfv = fminf(selfv, __shfl_xor(selfv, 32));

    if (l < 32) {
        int set = slice * 4 + w;
        #pragma unroll
        for (int ct = 0; ct < 4; ++ct) {
            int col = jb * 128 + ct * 32 + l;
            float* p = partial + ((size_t)set * NROWS + col) * 5;
            p[0] = Sa[ct]; p[1] = Sas[ct]; p[2] = Mp[ct]; p[3] = Mn[ct];
            p[4] = (ct == w) ? selfv : INFINITY;
        }
    }
}

// ---- finalize: merge partials, per-row loss terms, hinge mean ----
__global__ __launch_bounds__(256) void combine_kernel(const float* __restrict__ sq,
                                                      const int* __restrict__ tgt,
                                                      const int* __restrict__ hist,
                                                      const float* __restrict__ S_class,
                                                      const float* __restrict__ partial,
                                                      float* __restrict__ out,
                                                      int nSets) {
    __shared__ float scl[256];
    __shared__ float sAllSh;
    __shared__ float wsum[4];
    int tid = threadIdx.x;
    scl[tid] = S_class[tid];
    __syncthreads();
    if (tid < 64) {
        float s = scl[tid] + scl[tid + 64] + scl[tid + 128] + scl[tid + 192];
        for (int d = 32; d > 0; d >>= 1) s += __shfl_down(s, d, 64);
        if (tid == 0) sAllSh = s;
    }
    __syncthreads();
    float S_all = sAllSh;

    int j = blockIdx.x * 256 + tid;
    float sqj = sq[j];
    int tj = tgt[j];
    float Sa = 0.f, Sas = 0.f, Mp = -INFINITY, Mn = INFINITY, Sf = INFINITY;
    for (int s = 0; s < nSets; ++s) {
        const float* p = partial + ((size_t)s * NROWS + j) * 5;
        Sa += p[0]; Sas += p[1];
        Mp = fmaxf(Mp, p[2]); Mn = fminf(Mn, p[3]); Sf = fminf(Sf, p[4]);
    }
    float cntp = (float)hist[tj];
    float sum_all = S_all + (float)NROWS * sqj - 2.0f * Sa;
    float sum_p   = scl[tj] + cntp * sqj - 2.0f * Sas;
    float sum_n   = sum_all - sum_p;
    float d2maxp  = sqj + 2.0f * Mp;
    float d2minn  = sqj + 2.0f * Mn;
    float d2self  = sqj + 2.0f * Sf;
    float sigma_p = (sum_p - d2self) / (cntp - 1.0f);
    float dist_ap = d2maxp / sigma_p + 0.5f * logf(sigma_p);
    float sigma_n = sum_n / ((float)NROWS - cntp);
    float dist_an = d2minn / sigma_n + 0.5f * logf(sigma_n);
    float h = fmaxf(dist_ap - dist_an + MARGIN_F, 0.0f);

    for (int d = 32; d > 0; d >>= 1) h += __shfl_down(h, d, 64);
    int lane = tid & 63, wv = tid >> 6;
    if (lane == 0) wsum[wv] = h;
    __syncthreads();
    if (tid == 0)
        atomicAdd(out, (wsum[0] + wsum[1] + wsum[2] + wsum[3]) * (1.0f / NROWS));
}

extern "C" void kernel_launch(void* const* d_in, const int* in_sizes, int n_in,
                              void* d_out, int out_size, void* d_ws, size_t ws_size,
                              hipStream_t stream) {
    const float* X   = (const float*)d_in[0];
    const int*   tgt = (const int*)d_in[1];
    float* out = (float*)d_out;

    // ws layout (float units): hist[256](as int) | S_class[256] | sq[8192] |
    //   upk[8192] | Xbf[8192*128 bf16 = 524288 float slots] | partial[4G*8192*5]
    float* f = (float*)d_ws;
    int*   hist    = (int*)f;
    float* S_class = f + 256;
    float* sq      = f + 512;
    float* upk     = f + 8704;
    unsigned short* Xbf = (unsigned short*)(f + 16896);
    float* partial = f + 541184;

    int G = 8;   // j-slices; grid = 64 x G blocks, 64/G i-tiles each
    while (G > 1 &&
           ws_size < ((size_t)541184 + (size_t)4 * G * NROWS * 5) * sizeof(float))
        G >>= 1;
    int tps = 64 / G;

    hipMemsetAsync(out, 0, sizeof(float), stream);
    hipMemsetAsync(d_ws, 0, 2048, stream);   // hist + S_class
    prep_kernel<<<NROWS / 4, 256, 0, stream>>>(X, tgt, sq, upk, Xbf, S_class, hist);
    dist_kernel<<<dim3(64, G), 256, 0, stream>>>(Xbf, tgt, upk, partial, tps);
    combine_kernel<<<NROWS / 256, 256, 0, stream>>>(sq, tgt, hist, S_class, partial, out, 4 * G);
}

// Round 3
// 162.993 us; speedup vs baseline: 2.2034x; 1.2246x over previous
//
#include <hip/hip_runtime.h>
#include <math.h>

// TripletLoss round 3: class-sorted rows + XCD-local slices + analytic sums.
//
// Rows are counting-sorted by class. Per (sorted) column j:
//   d2_ij = sq_i + sq_j - 2*acc_ij = sq_j + 2*(u_i - acc),  u = sq/2
//   sum_all_j = N*sq_j + S_all     - 2*Sa_j   (Sa  = sum_i acc_ij, epilogue)
//   sum_p_j   = cnt*sq_j + S_class - 2*Sas_j  (Sas = sum_{same} acc, band tiles only)
//   max_p d2  = sq_j + 2*max_{i in [cs,ce)} (u_i - acc)
//   min_n d2  = sq_j + 2*min_{i not in [cs,ce)} (u_i - acc)
// Positives are the contiguous sorted range [cs_j, cs_j+wd_j); the dropped
// self element is the min positive (d2~0), never the max, and its ~0 value
// is absorbed analytically (error ~1e-5 relative).

#define NROWS 8192
#define NCLS 256
#define MARGIN_F 0.3f

typedef short bf16x8 __attribute__((ext_vector_type(8)));
typedef float f32x16 __attribute__((ext_vector_type(16)));
union U4B { uint4 u; bf16x8 h; };

__device__ __forceinline__ unsigned f2bf(float x) {
    unsigned u = __float_as_uint(x);
    return (u + 0x7fffu + ((u >> 16) & 1u)) >> 16;
}

// ---- K1: class histogram ----
__global__ __launch_bounds__(256) void histo_kernel(const int* __restrict__ tgt,
                                                    int* __restrict__ hist) {
    int i = blockIdx.x * 256 + threadIdx.x;
    atomicAdd(&hist[tgt[i]], 1);
}

// ---- K2: exclusive scan of hist -> off; zero cursors ----
__global__ __launch_bounds__(256) void scan_kernel(const int* __restrict__ hist,
                                                   int* __restrict__ off,
                                                   int* __restrict__ cursor) {
    __shared__ int sh[256];
    int tid = threadIdx.x;
    int v = hist[tid];
    sh[tid] = v;
    __syncthreads();
    for (int d = 1; d < 256; d <<= 1) {
        int t = (tid >= d) ? sh[tid - d] : 0;
        __syncthreads();
        sh[tid] += t;
        __syncthreads();
    }
    off[tid] = sh[tid] - v;     // exclusive prefix
    cursor[tid] = 0;
}

// ---- K3: convert fp32->bf16 and scatter rows into class-sorted order ----
__global__ __launch_bounds__(256) void scatter_kernel(
        const float* __restrict__ X, const int* __restrict__ tgt,
        const int* __restrict__ hist, const int* __restrict__ off,
        int* __restrict__ cursor, unsigned short* __restrict__ Xs,
        float* __restrict__ u_s, int* __restrict__ cls_s,
        int* __restrict__ csA, int* __restrict__ wdA,
        float* __restrict__ S_class, float* __restrict__ S_all) {
    int w = threadIdx.x >> 6, l = threadIdx.x & 63;
    int r = blockIdx.x * 4 + w;
    float2 v = ((const float2*)(X + (size_t)r * 128))[l];
    float s = v.x * v.x + v.y * v.y;
    for (int d = 32; d > 0; d >>= 1) s += __shfl_down(s, d, 64);
    float stot = __shfl(s, 0, 64);
    int c = 0, pos = 0;
    if (l == 0) {
        c = tgt[r];
        int rank = atomicAdd(&cursor[c], 1);
        pos = off[c] + rank;
    }
    c = __shfl(c, 0, 64);
    pos = __shfl(pos, 0, 64);
    ushort2 h;
    h.x = (unsigned short)f2bf(v.x);
    h.y = (unsigned short)f2bf(v.y);
    ((ushort2*)(Xs + (size_t)pos * 128))[l] = h;
    if (l == 0) {
        u_s[pos] = 0.5f * stot;
        cls_s[pos] = c;
        csA[pos] = off[c];
        wdA[pos] = hist[c];
        atomicAdd(&S_class[c], stot);
    }
    __shared__ float bs[4];
    if (l == 0) bs[w] = stot;
    __syncthreads();
    if (threadIdx.x == 0) atomicAdd(S_all, bs[0] + bs[1] + bs[2] + bs[3]);
}

// ---- K4: MFMA Gram + fused column stats ----
__global__ __launch_bounds__(256, 2) void dist_kernel(
        const unsigned short* __restrict__ Xs, const float* __restrict__ u_s,
        const int* __restrict__ csA, const int* __restrict__ wdA,
        float4* __restrict__ partial) {
    __shared__ uint4 As[128 * 16];
    __shared__ float ush[128];
    const int tid = threadIdx.x;
    const int w = tid >> 6, l = tid & 63, hl = l >> 5, l31 = l & 31;
    const int bx = blockIdx.x;
    const int slice = bx & 7;      // == XCD id under round-robin: slices share A
    const int jb = bx >> 3;

    // stage this block's 128 B-columns (32 KB) via LDS, swizzled
    {
        const uint4* src = (const uint4*)Xs + (size_t)jb * 128 * 16;
        #pragma unroll
        for (int s = 0; s < 8; ++s) {
            int g = s * 256 + tid, row = g >> 4, c = g & 15;
            As[row * 16 + (c ^ (row & 15))] = src[g];
        }
    }
    __syncthreads();
    bf16x8 Bf[4][8];
    int cs[4], wd[4];
    #pragma unroll
    for (int ct = 0; ct < 4; ++ct) {
        int colb = ct * 32 + l31;
        cs[ct] = csA[jb * 128 + colb];
        wd[ct] = wdA[jb * 128 + colb];
        #pragma unroll
        for (int kk = 0; kk < 8; ++kk) {
            U4B t; t.u = As[colb * 16 + ((kk * 2 + hl) ^ (colb & 15))];
            Bf[ct][kk] = t.h;
        }
    }

    float Sa[4] = {0.f, 0.f, 0.f, 0.f};
    float Ss[4] = {0.f, 0.f, 0.f, 0.f};
    float Mp[4] = {-INFINITY, -INFINITY, -INFINITY, -INFINITY};
    float Mn[4] = { INFINITY,  INFINITY,  INFINITY,  INFINITY};

    for (int t = 0; t < 8; ++t) {
        const int i0 = slice * 1024 + t * 128;
        __syncthreads();
        {
            const uint4* src = (const uint4*)Xs + (size_t)i0 * 16;
            #pragma unroll
            for (int s = 0; s < 8; ++s) {
                int g = s * 256 + tid, row = g >> 4, c = g & 15;
                As[row * 16 + (c ^ (row & 15))] = src[g];
            }
            if (tid < 128) ush[tid] = u_s[i0 + tid];
        }
        __syncthreads();

        float ur[16];
        #pragma unroll
        for (int r = 0; r < 16; ++r)
            ur[r] = ush[w * 32 + (r & 3) + 8 * (r >> 2) + 4 * hl];

        f32x16 acc[4];
        #pragma unroll
        for (int ct = 0; ct < 4; ++ct) acc[ct] = (f32x16)0.0f;
        const int arow = w * 32 + l31;
        #pragma unroll
        for (int kk = 0; kk < 8; ++kk) {
            U4B a; a.u = As[arow * 16 + ((kk * 2 + hl) ^ (arow & 15))];
            #pragma unroll
            for (int ct = 0; ct < 4; ++ct)
                acc[ct] = __builtin_amdgcn_mfma_f32_32x32x16_bf16(a.h, Bf[ct][kk], acc[ct], 0, 0, 0);
        }

        const int rowb = i0 + w * 32 + 4 * hl;
        #pragma unroll
        for (int ct = 0; ct < 4; ++ct) {
            bool bl = (cs[ct] < i0 + 128) && (cs[ct] + wd[ct] > i0);
            if (__any(bl)) {
                // band tile: exact range mask per element
                int tb = rowb - cs[ct];
                unsigned wdu = (unsigned)wd[ct];
                #pragma unroll
                for (int r = 0; r < 16; ++r) {
                    float a = acc[ct][r];
                    float v = ur[r] - a;
                    bool in = (unsigned)(tb + (r & 3) + 8 * (r >> 2)) < wdu;
                    Sa[ct] += a;
                    Ss[ct] += in ? a : 0.0f;
                    Mp[ct] = fmaxf(Mp[ct], in ? v : -INFINITY);
                    Mn[ct] = in ? Mn[ct] : fminf(Mn[ct], v);
                }
            } else {
                // pure-negative tile: 5 VALU per 2 elements
                #pragma unroll
                for (int r = 0; r < 16; r += 2) {
                    float a1 = acc[ct][r], a2 = acc[ct][r + 1];
                    float v1 = ur[r] - a1, v2 = ur[r + 1] - a2;
                    Mn[ct] = fminf(Mn[ct], fminf(v1, v2));
                    Sa[ct] += (a1 + a2);
                }
            }
        }
    }

    // merge half-lanes, then the 4 waves via LDS, then write per-slice partial
    #pragma unroll
    for (int ct = 0; ct < 4; ++ct) {
        Sa[ct] += __shfl_xor(Sa[ct], 32, 64);
        Ss[ct] += __shfl_xor(Ss[ct], 32, 64);
        Mp[ct] = fmaxf(Mp[ct], __shfl_xor(Mp[ct], 32, 64));
        Mn[ct] = fminf(Mn[ct], __shfl_xor(Mn[ct], 32, 64));
    }
    __syncthreads();
    float4* sm = (float4*)As;     // [128 cols][4 waves]
    if (l < 32) {
        #pragma unroll
        for (int ct = 0; ct < 4; ++ct)
            sm[(ct * 32 + l31) * 4 + w] = make_float4(Sa[ct], Ss[ct], Mp[ct], Mn[ct]);
    }
    __syncthreads();
    if (tid < 128) {
        float4 a = sm[tid * 4 + 0], b = sm[tid * 4 + 1];
        float4 c2 = sm[tid * 4 + 2], d = sm[tid * 4 + 3];
        float4 o;
        o.x = a.x + b.x + c2.x + d.x;
        o.y = a.y + b.y + c2.y + d.y;
        o.z = fmaxf(fmaxf(a.z, b.z), fmaxf(c2.z, d.z));
        o.w = fminf(fminf(a.w, b.w), fminf(c2.w, d.w));
        partial[(size_t)(jb * 128 + tid) * 8 + slice] = o;
    }
}

// ---- K5: per-row loss, block sums (wave per row, coalesced partials) ----
__global__ __launch_bounds__(256) void combine_kernel(
        const float* __restrict__ u_s, const int* __restrict__ cls_s,
        const int* __restrict__ hist, const float* __restrict__ S_class,
        const float* __restrict__ S_all, const float4* __restrict__ partial,
        float* __restrict__ blocksum) {
    int w = threadIdx.x >> 6, l = threadIdx.x & 63;
    int row = blockIdx.x * 4 + w;
    float4 p = partial[(size_t)row * 8 + (l & 7)];
    #pragma unroll
    for (int d = 1; d < 8; d <<= 1) {
        p.x += __shfl_xor(p.x, d, 64);
        p.y += __shfl_xor(p.y, d, 64);
        p.z = fmaxf(p.z, __shfl_xor(p.z, d, 64));
        p.w = fminf(p.w, __shfl_xor(p.w, d, 64));
    }
    float sq = 2.0f * u_s[row];
    int c = cls_s[row];
    float cnt = (float)hist[c];
    float sumall = (float)NROWS * sq + *S_all - 2.0f * p.x;
    float sump = cnt * sq + S_class[c] - 2.0f * p.y;
    float sumn = sumall - sump;
    float sigp = sump / (cnt - 1.0f);
    float sign_ = sumn / ((float)NROWS - cnt);
    float ap = (sq + 2.0f * p.z) / sigp + 0.5f * __logf(sigp);
    float an = (sq + 2.0f * p.w) / sign_ + 0.5f * __logf(sign_);
    float h = fmaxf(ap - an + MARGIN_F, 0.0f);
    __shared__ float hs[4];
    if (l == 0) hs[w] = h;
    __syncthreads();
    if (threadIdx.x == 0) blocksum[blockIdx.x] = hs[0] + hs[1] + hs[2] + hs[3];
}

// ---- K6: final mean ----
__global__ __launch_bounds__(256) void final_kernel(const float* __restrict__ blocksum,
                                                    float* __restrict__ out) {
    int tid = threadIdx.x;
    float s = 0.f;
    #pragma unroll
    for (int k = 0; k < 8; ++k) s += blocksum[k * 256 + tid];
    for (int d = 32; d > 0; d >>= 1) s += __shfl_down(s, d, 64);
    __shared__ float ws2[4];
    int l = tid & 63, w = tid >> 6;
    if (l == 0) ws2[w] = s;
    __syncthreads();
    if (tid == 0) out[0] = (ws2[0] + ws2[1] + ws2[2] + ws2[3]) * (1.0f / NROWS);
}

extern "C" void kernel_launch(void* const* d_in, const int* in_sizes, int n_in,
                              void* d_out, int out_size, void* d_ws, size_t ws_size,
                              hipStream_t stream) {
    const float* X = (const float*)d_in[0];
    const int* tgt = (const int*)d_in[1];
    float* out = (float*)d_out;

    float* f = (float*)d_ws;
    int* hist = (int*)f;                              // [0, 256)
    float* S_class = f + 256;                         // [256, 512)
    float* S_all = f + 512;                           // [512, 528) (padded)
    int* off = (int*)(f + 528);                       // [528, 784)
    int* cursor = (int*)(f + 784);                    // [784, 1040)
    float* blocksum = f + 1040;                       // [1040, 3088)
    float* u_s = f + 3088;                            // [3088, 11280)
    int* cls_s = (int*)(f + 11280);                   // [11280, 19472)
    int* csA = (int*)(f + 19472);                     // [19472, 27664)
    int* wdA = (int*)(f + 27664);                     // [27664, 35856)
    unsigned short* Xs = (unsigned short*)(f + 35856);// [35856, 560144) bf16[1M]
    float4* partial = (float4*)(f + 560144);          // [560144, 822288)  ~3.3MB total

    hipMemsetAsync(d_ws, 0, 2080, stream);            // hist + S_class + S_all
    histo_kernel<<<32, 256, 0, stream>>>(tgt, hist);
    scan_kernel<<<1, 256, 0, stream>>>(hist, off, cursor);
    scatter_kernel<<<2048, 256, 0, stream>>>(X, tgt, hist, off, cursor, Xs, u_s,
                                             cls_s, csA, wdA, S_class, S_all);
    dist_kernel<<<512, 256, 0, stream>>>(Xs, u_s, csA, wdA, partial);
    combine_kernel<<<2048, 256, 0, stream>>>(u_s, cls_s, hist, S_class, S_all,
                                             partial, blocksum);
    final_kernel<<<1, 256, 0, stream>>>(blocksum, out);
}

// Round 4
// 130.777 us; speedup vs baseline: 2.7462x; 1.2463x over previous
//
#include <hip/hip_runtime.h>
#include <math.h>

// TripletLoss round 4: zero global atomics. Deterministic counting sort
// (LDS histograms + single-block scan) + 16-slice XCD-local MFMA Gram.
//
// Per sorted column j: d2_ij = sq_j + 2*(u_i - acc_ij), u = sq/2.
//   sum_all_j = N*sq_j + S_all     - 2*Sa_j
//   sum_p_j   = cnt*sq_j + S_class - 2*Ss_j   (band tiles only)
//   max_p / min_n from streaming max/min of (u_i - acc).
// Self term absorbed analytically (d2_self ~ bf16 noise, negligible vs sums).

#define NROWS 8192
#define MARGIN_F 0.3f

typedef short bf16x8 __attribute__((ext_vector_type(8)));
typedef float f32x16 __attribute__((ext_vector_type(16)));
union U4B { uint4 u; bf16x8 h; };

__device__ __forceinline__ unsigned short f2bf(float x) {
    unsigned u = __float_as_uint(x);
    return (unsigned short)((u + 0x7fffu + ((u >> 16) & 1u)) >> 16);
}

// ---- K1: per-row sq (all 256 blocks) + per-chunk LDS histogram (blocks<64) ----
__global__ __launch_bounds__(256) void prep_kernel(const float* __restrict__ X,
                                                   const int* __restrict__ tgt,
                                                   float* __restrict__ sq,
                                                   int* __restrict__ bh) {
    __shared__ int lh[256];
    int tid = threadIdx.x;
    lh[tid] = 0;
    __syncthreads();
    if (blockIdx.x < 64 && tid < 128)
        atomicAdd(&lh[tgt[blockIdx.x * 128 + tid]], 1);
    int w = tid >> 6, l = tid & 63;
    int row0 = blockIdx.x * 32;
    #pragma unroll
    for (int i = 0; i < 8; ++i) {
        int r = row0 + w * 8 + i;
        float2 v = ((const float2*)X)[(size_t)r * 64 + l];
        float s = v.x * v.x + v.y * v.y;
        for (int d = 32; d > 0; d >>= 1) s += __shfl_down(s, d, 64);
        if (l == 0) sq[r] = s;
    }
    __syncthreads();
    if (blockIdx.x < 64) bh[blockIdx.x * 256 + tid] = lh[tid];
}

// ---- K2: hist, offsets, per-chunk bases, S_class, S_all (one block) ----
__global__ __launch_bounds__(256) void offsets_kernel(const int* __restrict__ bh,
                                                      const int* __restrict__ tgt,
                                                      const float* __restrict__ sq,
                                                      int* __restrict__ hist,
                                                      int* __restrict__ offg,
                                                      int* __restrict__ boff,
                                                      float* __restrict__ S_class,
                                                      float* __restrict__ S_all) {
    __shared__ int sh[256];
    __shared__ float scl[256];
    __shared__ float red[4];
    int c = threadIdx.x;
    int h = 0;
    for (int b = 0; b < 64; ++b) h += bh[b * 256 + c];
    hist[c] = h;
    sh[c] = h;
    scl[c] = 0.0f;
    __syncthreads();
    for (int d = 1; d < 256; d <<= 1) {
        int t = (c >= d) ? sh[c - d] : 0;
        __syncthreads();
        sh[c] += t;
        __syncthreads();
    }
    int off = sh[c] - h;      // exclusive prefix
    offg[c] = off;
    for (int i = 0; i < 32; ++i) {
        int r = i * 256 + c;
        atomicAdd(&scl[tgt[r]], sq[r]);    // LDS float atomic
    }
    __syncthreads();
    float sc = scl[c];
    S_class[c] = sc;
    float t2 = sc;
    for (int d = 32; d > 0; d >>= 1) t2 += __shfl_down(t2, d, 64);
    if ((c & 63) == 0) red[c >> 6] = t2;
    __syncthreads();
    if (c == 0) S_all[0] = red[0] + red[1] + red[2] + red[3];
    int run = off;
    for (int b = 0; b < 64; ++b) {
        boff[b * 256 + c] = run;
        run += bh[b * 256 + c];
    }
}

// ---- K3: scatter rows into class-sorted bf16 array (LDS cursors only) ----
__global__ __launch_bounds__(256) void scatter_kernel(
        const float* __restrict__ X, const int* __restrict__ tgt,
        const float* __restrict__ sq, const int* __restrict__ hist,
        const int* __restrict__ offg, const int* __restrict__ boff,
        unsigned short* __restrict__ Xs, float* __restrict__ u_s,
        int* __restrict__ cls_s, int* __restrict__ csA, int* __restrict__ wdA) {
    __shared__ int cur[256];
    __shared__ int pos_sh[128];
    int tid = threadIdx.x;
    cur[tid] = boff[blockIdx.x * 256 + tid];
    __syncthreads();
    int row0 = blockIdx.x * 128;
    if (tid < 128) {
        int c = tgt[row0 + tid];
        int p = atomicAdd(&cur[c], 1);     // LDS atomic, ~2 per class per block
        pos_sh[tid] = p;
        u_s[p] = 0.5f * sq[row0 + tid];
        cls_s[p] = c;
        csA[p] = offg[c];
        wdA[p] = hist[c];
    }
    __syncthreads();
    int w = tid >> 6, l = tid & 63;
    #pragma unroll 4
    for (int i = 0; i < 32; ++i) {
        int rl = w * 32 + i;
        int p = pos_sh[rl];
        float2 v = ((const float2*)X)[(size_t)(row0 + rl) * 64 + l];
        ushort2 h2;
        h2.x = f2bf(v.x);
        h2.y = f2bf(v.y);
        ((ushort2*)Xs)[(size_t)p * 64 + l] = h2;
    }
}

// ---- K4: MFMA Gram + fused column stats ----
__global__ __launch_bounds__(256, 2) void dist_kernel(
        const unsigned short* __restrict__ Xs, const float* __restrict__ u_s,
        const int* __restrict__ csA, const int* __restrict__ wdA,
        float4* __restrict__ partial, int ns_mask, int jb_shift, int tiles) {
    __shared__ uint4 As[128 * 16];
    __shared__ float ush[128];
    const int tid = threadIdx.x;
    const int w = tid >> 6, l = tid & 63, hl = l >> 5, l31 = l & 31;
    const int bx = blockIdx.x;
    const int slice = bx & ns_mask;    // low 3 bits = XCD id: slices share A in L2
    const int jb = bx >> jb_shift;

    // stage this block's 128 B-columns via LDS (swizzled), build register frags
    {
        const uint4* src = (const uint4*)Xs + (size_t)jb * 128 * 16;
        #pragma unroll
        for (int s = 0; s < 8; ++s) {
            int g = s * 256 + tid, row = g >> 4, c = g & 15;
            As[row * 16 + (c ^ (row & 15))] = src[g];
        }
    }
    __syncthreads();
    bf16x8 Bf[4][8];
    int cs[4], wd[4];
    #pragma unroll
    for (int ct = 0; ct < 4; ++ct) {
        int colb = ct * 32 + l31;
        cs[ct] = csA[jb * 128 + colb];
        wd[ct] = wdA[jb * 128 + colb];
        #pragma unroll
        for (int kk = 0; kk < 8; ++kk) {
            U4B t; t.u = As[colb * 16 + ((kk * 2 + hl) ^ (colb & 15))];
            Bf[ct][kk] = t.h;
        }
    }

    float Sa[4] = {0.f, 0.f, 0.f, 0.f};
    float Ss[4] = {0.f, 0.f, 0.f, 0.f};
    float Mp[4] = {-INFINITY, -INFINITY, -INFINITY, -INFINITY};
    float Mn[4] = { INFINITY,  INFINITY,  INFINITY,  INFINITY};

    for (int t = 0; t < tiles; ++t) {
        const int i0 = (slice * tiles + t) * 128;
        __syncthreads();
        {
            const uint4* src = (const uint4*)Xs + (size_t)i0 * 16;
            #pragma unroll
            for (int s = 0; s < 8; ++s) {
                int g = s * 256 + tid, row = g >> 4, c = g & 15;
                As[row * 16 + (c ^ (row & 15))] = src[g];
            }
            if (tid < 128) ush[tid] = u_s[i0 + tid];
        }
        __syncthreads();

        float ur[16];
        #pragma unroll
        for (int r = 0; r < 16; ++r)
            ur[r] = ush[w * 32 + (r & 3) + 8 * (r >> 2) + 4 * hl];

        f32x16 acc[4];
        #pragma unroll
        for (int ct = 0; ct < 4; ++ct) acc[ct] = (f32x16)0.0f;
        const int arow = w * 32 + l31;
        #pragma unroll
        for (int kk = 0; kk < 8; ++kk) {
            U4B a; a.u = As[arow * 16 + ((kk * 2 + hl) ^ (arow & 15))];
            #pragma unroll
            for (int ct = 0; ct < 4; ++ct)
                acc[ct] = __builtin_amdgcn_mfma_f32_32x32x16_bf16(a.h, Bf[ct][kk], acc[ct], 0, 0, 0);
        }

        const int rowb = i0 + w * 32 + 4 * hl;
        #pragma unroll
        for (int ct = 0; ct < 4; ++ct) {
            bool bl = (cs[ct] < i0 + 128) && (cs[ct] + wd[ct] > i0);
            if (__any(bl)) {
                int tb = rowb - cs[ct];
                unsigned wdu = (unsigned)wd[ct];
                #pragma unroll
                for (int r = 0; r < 16; ++r) {
                    float a = acc[ct][r];
                    float v = ur[r] - a;
                    bool in = (unsigned)(tb + (r & 3) + 8 * (r >> 2)) < wdu;
                    Sa[ct] += a;
                    Ss[ct] += in ? a : 0.0f;
                    Mp[ct] = fmaxf(Mp[ct], in ? v : -INFINITY);
                    Mn[ct] = in ? Mn[ct] : fminf(Mn[ct], v);
                }
            } else {
                #pragma unroll
                for (int r = 0; r < 16; r += 2) {
                    float a1 = acc[ct][r], a2 = acc[ct][r + 1];
                    float v1 = ur[r] - a1, v2 = ur[r + 1] - a2;
                    Mn[ct] = fminf(Mn[ct], fminf(v1, v2));
                    Sa[ct] += (a1 + a2);
                }
            }
        }
    }

    #pragma unroll
    for (int ct = 0; ct < 4; ++ct) {
        Sa[ct] += __shfl_xor(Sa[ct], 32, 64);
        Ss[ct] += __shfl_xor(Ss[ct], 32, 64);
        Mp[ct] = fmaxf(Mp[ct], __shfl_xor(Mp[ct], 32, 64));
        Mn[ct] = fminf(Mn[ct], __shfl_xor(Mn[ct], 32, 64));
    }
    __syncthreads();
    float4* sm = (float4*)As;     // [128 cols][4 waves]
    if (l < 32) {
        #pragma unroll
        for (int ct = 0; ct < 4; ++ct)
            sm[(ct * 32 + l31) * 4 + w] = make_float4(Sa[ct], Ss[ct], Mp[ct], Mn[ct]);
    }
    __syncthreads();
    if (tid < 128) {
        float4 a = sm[tid * 4 + 0], b = sm[tid * 4 + 1];
        float4 c2 = sm[tid * 4 + 2], d = sm[tid * 4 + 3];
        float4 o;
        o.x = a.x + b.x + c2.x + d.x;
        o.y = a.y + b.y + c2.y + d.y;
        o.z = fmaxf(fmaxf(a.z, b.z), fmaxf(c2.z, d.z));
        o.w = fminf(fminf(a.w, b.w), fminf(c2.w, d.w));
        partial[(size_t)slice * NROWS + jb * 128 + tid] = o;   // coalesced
    }
}

// ---- K5: per-row loss (thread per row), block sums ----
__global__ __launch_bounds__(256) void combine_kernel(
        const float* __restrict__ u_s, const int* __restrict__ cls_s,
        const int* __restrict__ wdA, const float* __restrict__ S_class,
        const float* __restrict__ S_all, const float4* __restrict__ partial,
        float* __restrict__ blocksum, int ns) {
    int tid = threadIdx.x;
    int j = blockIdx.x * 256 + tid;
    float Sa = 0.f, Ss = 0.f, Mp = -INFINITY, Mn = INFINITY;
    for (int s = 0; s < ns; ++s) {
        float4 p = partial[(size_t)s * NROWS + j];
        Sa += p.x; Ss += p.y;
        Mp = fmaxf(Mp, p.z); Mn = fminf(Mn, p.w);
    }
    float sqj = 2.0f * u_s[j];
    int c = cls_s[j];
    float cnt = (float)wdA[j];
    float sumall = (float)NROWS * sqj + S_all[0] - 2.0f * Sa;
    float sump = cnt * sqj + S_class[c] - 2.0f * Ss;
    float sumn = sumall - sump;
    float sigp = sump / (cnt - 1.0f);
    float sign_ = sumn / ((float)NROWS - cnt);
    float ap = (sqj + 2.0f * Mp) / sigp + 0.5f * __logf(sigp);
    float an = (sqj + 2.0f * Mn) / sign_ + 0.5f * __logf(sign_);
    float h = fmaxf(ap - an + MARGIN_F, 0.0f);
    for (int d = 32; d > 0; d >>= 1) h += __shfl_down(h, d, 64);
    __shared__ float hs[4];
    int l = tid & 63, w = tid >> 6;
    if (l == 0) hs[w] = h;
    __syncthreads();
    if (tid == 0) blocksum[blockIdx.x] = hs[0] + hs[1] + hs[2] + hs[3];
}

// ---- K6: final mean ----
__global__ __launch_bounds__(64) void final_kernel(const float* __restrict__ blocksum,
                                                   float* __restrict__ out) {
    int tid = threadIdx.x;
    float s = (tid < 32) ? blocksum[tid] : 0.0f;
    for (int d = 32; d > 0; d >>= 1) s += __shfl_down(s, d, 64);
    if (tid == 0) out[0] = s * (1.0f / NROWS);
}

extern "C" void kernel_launch(void* const* d_in, const int* in_sizes, int n_in,
                              void* d_out, int out_size, void* d_ws, size_t ws_size,
                              hipStream_t stream) {
    const float* X = (const float*)d_in[0];
    const int* tgt = (const int*)d_in[1];
    float* out = (float*)d_out;

    float* f = (float*)d_ws;
    int*   hist    = (int*)f;                 // [0,256)
    int*   offg    = (int*)(f + 256);         // [256,512)
    float* S_class = f + 512;                 // [512,768)
    float* S_all   = f + 768;                 // [768,784)
    int*   bh      = (int*)(f + 1024);        // [1024,17408)
    int*   boff    = (int*)(f + 17408);       // [17408,33792)
    float* sq      = f + 33792;               // [33792,41984)
    float* u_s     = f + 41984;               // [41984,50176)
    int*   cls_s   = (int*)(f + 50176);       // [50176,58368)
    int*   csA     = (int*)(f + 58368);       // [58368,66560)
    int*   wdA     = (int*)(f + 66560);       // [66560,74752)
    float* blocksum = f + 74752;              // [74752,74784)
    unsigned short* Xs = (unsigned short*)(f + 74784); // bf16[1M] -> [74784,599072)
    float4* partial = (float4*)(f + 599072);  // ns*8192 float4

    int ns = 16;
    while (ns > 2 && ws_size < ((size_t)599072 + (size_t)ns * NROWS * 4) * sizeof(float))
        ns >>= 1;
    int shift = (ns == 16) ? 4 : (ns == 8) ? 3 : 2;
    int tiles = 64 / ns;

    prep_kernel<<<256, 256, 0, stream>>>(X, tgt, sq, bh);
    offsets_kernel<<<1, 256, 0, stream>>>(bh, tgt, sq, hist, offg, boff, S_class, S_all);
    scatter_kernel<<<64, 256, 0, stream>>>(X, tgt, sq, hist, offg, boff, Xs, u_s,
                                           cls_s, csA, wdA);
    dist_kernel<<<64 * ns, 256, 0, stream>>>(Xs, u_s, csA, wdA, partial,
                                             ns - 1, shift, tiles);
    combine_kernel<<<32, 256, 0, stream>>>(u_s, cls_s, wdA, S_class, S_all,
                                           partial, blocksum, ns);
    final_kernel<<<1, 64, 0, stream>>>(blocksum, out);
}

// Round 5
// 119.871 us; speedup vs baseline: 2.9961x; 1.0910x over previous
//
#include <hip/hip_runtime.h>
#include <math.h>

// TripletLoss round 5: unsorted tag-mask epilogue, spill-free dist (ct=2),
// 5-node graph (memset + 4 kernels).
//
// Per column j: d2_ij = sq_j + 2*(u_i - acc_ij), u = sq/2 (tag in low 8 mantissa bits).
//   sum_all_j = N*sq_j + S_all     - 2*Sa_j
//   sum_p_j   = cnt*sq_j + S_class - 2*Ss_j
//   max_p d2  = sq_j + 2*max_same(u_i - acc)   (self can't win: its v ~ -sq_j/2)
//   min_n d2  = sq_j + 2*min_diff(u_i - acc)
// Self positive absorbed analytically in sum_p (bf16 noise / (cnt-1) ~ 1e-5 rel).

#define NROWS 8192
#define MARGIN_F 0.3f

typedef short bf16x8 __attribute__((ext_vector_type(8)));
typedef float f32x16 __attribute__((ext_vector_type(16)));
union U4B { uint4 u; bf16x8 h; };

__device__ __forceinline__ unsigned short f2bf(float x) {
    unsigned u = __float_as_uint(x);
    return (unsigned short)((u + 0x7fffu + ((u >> 16) & 1u)) >> 16);
}

// ---- K1: bf16 convert, sq, tagged u, hist/S_class atomics, per-block sums ----
__global__ __launch_bounds__(256) void prep_kernel(const float* __restrict__ X,
                                                   const int* __restrict__ tgt,
                                                   float* __restrict__ sq,
                                                   float* __restrict__ upk,
                                                   unsigned short* __restrict__ Xbf,
                                                   int* __restrict__ hist,
                                                   float* __restrict__ S_class,
                                                   float* __restrict__ bsum) {
    int tid = threadIdx.x, w = tid >> 6, l = tid & 63;
    int row0 = blockIdx.x * 32 + w * 8;
    float rs = 0.0f;
    #pragma unroll
    for (int i = 0; i < 8; ++i) {
        int r = row0 + i;
        float2 v = ((const float2*)X)[(size_t)r * 64 + l];
        ushort2 h2;
        h2.x = f2bf(v.x);
        h2.y = f2bf(v.y);
        ((ushort2*)Xbf)[(size_t)r * 64 + l] = h2;
        float s = v.x * v.x + v.y * v.y;
        for (int d = 32; d > 0; d >>= 1) s += __shfl_down(s, d, 64);
        if (l == 0) {
            sq[r] = s;
            rs += s;
            int c = tgt[r];
            upk[r] = __uint_as_float((__float_as_uint(0.5f * s) & 0xffffff00u) | (unsigned)c);
            atomicAdd(&hist[c], 1);
            atomicAdd(&S_class[c], s);
        }
    }
    __shared__ float bs[4];
    if (l == 0) bs[w] = rs;
    __syncthreads();
    if (tid == 0) bsum[blockIdx.x] = bs[0] + bs[1] + bs[2] + bs[3];
}

// ---- K2: MFMA Gram + fused column stats (64 cols/block, no spills) ----
__global__ __launch_bounds__(256, 3) void dist_kernel(
        const unsigned short* __restrict__ Xbf, const int* __restrict__ tgt,
        const float* __restrict__ upk, float4* __restrict__ partial,
        int ns_mask, int jb_shift, int tiles) {
    __shared__ uint4 As[128 * 16];
    __shared__ float ush[128];
    const int tid = threadIdx.x;
    const int w = tid >> 6, l = tid & 63, hl = l >> 5, l31 = l & 31;
    const int bx = blockIdx.x;
    const int slice = bx & ns_mask;   // bx%8 = XCD id -> XCD k hosts slices {k, k+8}
    const int jb = bx >> jb_shift;    // 64-col strip

    // stage this block's 64 B-columns (16 KB) via LDS, build register frags
    {
        const uint4* src = (const uint4*)Xbf + (size_t)jb * 64 * 16;
        #pragma unroll
        for (int s = 0; s < 4; ++s) {
            int g = s * 256 + tid, row = g >> 4, c = g & 15;
            As[row * 16 + (c ^ (row & 15))] = src[g];
        }
    }
    __syncthreads();
    bf16x8 Bf[2][8];
    int tjt[2];
    #pragma unroll
    for (int ct = 0; ct < 2; ++ct) {
        int colb = ct * 32 + l31;
        tjt[ct] = tgt[jb * 64 + colb];
        #pragma unroll
        for (int kk = 0; kk < 8; ++kk) {
            U4B t; t.u = As[colb * 16 + ((kk * 2 + hl) ^ (colb & 15))];
            Bf[ct][kk] = t.h;
        }
    }

    float Sa[2] = {0.f, 0.f};
    float Ss[2] = {0.f, 0.f};
    float Mp[2] = {-INFINITY, -INFINITY};
    float Mn[2] = { INFINITY,  INFINITY};

    for (int t = 0; t < tiles; ++t) {
        const int i0 = (slice * tiles + t) * 128;
        __syncthreads();
        {
            const uint4* src = (const uint4*)Xbf + (size_t)i0 * 16;
            #pragma unroll
            for (int s = 0; s < 8; ++s) {
                int g = s * 256 + tid, row = g >> 4, c = g & 15;
                As[row * 16 + (c ^ (row & 15))] = src[g];
            }
            if (tid < 128) ush[tid] = upk[i0 + tid];
        }
        __syncthreads();

        float ur[16];
        #pragma unroll
        for (int r = 0; r < 16; ++r)
            ur[r] = ush[w * 32 + (r & 3) + 8 * (r >> 2) + 4 * hl];

        f32x16 acc[2];
        acc[0] = (f32x16)0.0f;
        acc[1] = (f32x16)0.0f;
        const int arow = w * 32 + l31;
        #pragma unroll
        for (int kk = 0; kk < 8; ++kk) {
            U4B a; a.u = As[arow * 16 + ((kk * 2 + hl) ^ (arow & 15))];
            acc[0] = __builtin_amdgcn_mfma_f32_32x32x16_bf16(a.h, Bf[0][kk], acc[0], 0, 0, 0);
            acc[1] = __builtin_amdgcn_mfma_f32_32x32x16_bf16(a.h, Bf[1][kk], acc[1], 0, 0, 0);
        }

        #pragma unroll
        for (int ct = 0; ct < 2; ++ct) {
            const int tt = tjt[ct];
            #pragma unroll
            for (int r = 0; r < 16; ++r) {
                float a = acc[ct][r];
                float v = ur[r] - a;
                bool same = ((__float_as_int(ur[r]) & 0xff) == tt);
                Sa[ct] += a;
                Ss[ct] += same ? a : 0.0f;
                Mp[ct] = fmaxf(Mp[ct], same ? v : -INFINITY);
                Mn[ct] = same ? Mn[ct] : fminf(Mn[ct], v);
            }
        }
    }

    // merge half-lanes, then 4 waves via LDS, write coalesced partial
    #pragma unroll
    for (int ct = 0; ct < 2; ++ct) {
        Sa[ct] += __shfl_xor(Sa[ct], 32, 64);
        Ss[ct] += __shfl_xor(Ss[ct], 32, 64);
        Mp[ct] = fmaxf(Mp[ct], __shfl_xor(Mp[ct], 32, 64));
        Mn[ct] = fminf(Mn[ct], __shfl_xor(Mn[ct], 32, 64));
    }
    __syncthreads();
    float4* sm = (float4*)As;     // [64 cols][4 waves]
    if (l < 32) {
        #pragma unroll
        for (int ct = 0; ct < 2; ++ct)
            sm[(ct * 32 + l31) * 4 + w] = make_float4(Sa[ct], Ss[ct], Mp[ct], Mn[ct]);
    }
    __syncthreads();
    if (tid < 64) {
        float4 a = sm[tid * 4 + 0], b = sm[tid * 4 + 1];
        float4 c2 = sm[tid * 4 + 2], d = sm[tid * 4 + 3];
        float4 o;
        o.x = a.x + b.x + c2.x + d.x;
        o.y = a.y + b.y + c2.y + d.y;
        o.z = fmaxf(fmaxf(a.z, b.z), fmaxf(c2.z, d.z));
        o.w = fminf(fminf(a.w, b.w), fminf(c2.w, d.w));
        partial[(size_t)slice * NROWS + jb * 64 + tid] = o;
    }
}

// ---- K3: per-row loss (thread per row), block sums ----
__global__ __launch_bounds__(256) void combine_kernel(
        const float* __restrict__ sq, const int* __restrict__ tgt,
        const int* __restrict__ hist, const float* __restrict__ S_class,
        const float* __restrict__ bsum, const float4* __restrict__ partial,
        float* __restrict__ blocksum, int ns) {
    __shared__ float red[4];
    __shared__ float hs[4];
    int tid = threadIdx.x, l = tid & 63, w = tid >> 6;

    // S_all = sum of prep's 256 per-block sums
    float b = bsum[tid];
    for (int d = 32; d > 0; d >>= 1) b += __shfl_down(b, d, 64);
    if (l == 0) red[w] = b;
    __syncthreads();
    float S_all = red[0] + red[1] + red[2] + red[3];

    int j = blockIdx.x * 256 + tid;
    float Sa = 0.f, Ss = 0.f, Mp = -INFINITY, Mn = INFINITY;
    for (int s = 0; s < ns; ++s) {
        float4 p = partial[(size_t)s * NROWS + j];
        Sa += p.x; Ss += p.y;
        Mp = fmaxf(Mp, p.z); Mn = fminf(Mn, p.w);
    }
    float sqj = sq[j];
    int c = tgt[j];
    float cnt = (float)hist[c];
    float sumall = (float)NROWS * sqj + S_all - 2.0f * Sa;
    float sump = cnt * sqj + S_class[c] - 2.0f * Ss;
    float sumn = sumall - sump;
    float sigp = sump / (cnt - 1.0f);
    float sign_ = sumn / ((float)NROWS - cnt);
    float ap = (sqj + 2.0f * Mp) / sigp + 0.5f * __logf(sigp);
    float an = (sqj + 2.0f * Mn) / sign_ + 0.5f * __logf(sign_);
    float h = fmaxf(ap - an + MARGIN_F, 0.0f);
    for (int d = 32; d > 0; d >>= 1) h += __shfl_down(h, d, 64);
    if (l == 0) hs[w] = h;
    __syncthreads();
    if (tid == 0) blocksum[blockIdx.x] = hs[0] + hs[1] + hs[2] + hs[3];
}

// ---- K4: final mean ----
__global__ __launch_bounds__(64) void final_kernel(const float* __restrict__ blocksum,
                                                   float* __restrict__ out) {
    int tid = threadIdx.x;
    float s = (tid < 32) ? blocksum[tid] : 0.0f;
    for (int d = 32; d > 0; d >>= 1) s += __shfl_down(s, d, 64);
    if (tid == 0) out[0] = s * (1.0f / NROWS);
}

extern "C" void kernel_launch(void* const* d_in, const int* in_sizes, int n_in,
                              void* d_out, int out_size, void* d_ws, size_t ws_size,
                              hipStream_t stream) {
    const float* X = (const float*)d_in[0];
    const int* tgt = (const int*)d_in[1];
    float* out = (float*)d_out;

    float* f = (float*)d_ws;
    int*   hist     = (int*)f;                 // [0,256)      memset 0
    float* S_class  = f + 256;                 // [256,512)    memset 0
    float* bsum     = f + 512;                 // [512,768)
    float* blocksum = f + 768;                 // [768,800)
    float* sq       = f + 1024;                // [1024,9216)
    float* upk      = f + 9216;                // [9216,17408)
    unsigned short* Xbf = (unsigned short*)(f + 17408);  // bf16[1M] -> [17408,541696)
    float4* partial = (float4*)(f + 541696);   // ns*8192 float4

    int ns = 16;
    while (ns > 2 && ws_size < ((size_t)541696 + (size_t)ns * NROWS * 4) * sizeof(float))
        ns >>= 1;
    int shift = (ns == 16) ? 4 : (ns == 8) ? 3 : 2;
    int tiles = 64 / ns;

    hipMemsetAsync(d_ws, 0, 2048, stream);     // hist + S_class
    prep_kernel<<<256, 256, 0, stream>>>(X, tgt, sq, upk, Xbf, hist, S_class, bsum);
    dist_kernel<<<128 * ns, 256, 0, stream>>>(Xbf, tgt, upk, partial,
                                              ns - 1, shift, tiles);
    combine_kernel<<<32, 256, 0, stream>>>(sq, tgt, hist, S_class, bsum,
                                           partial, blocksum, ns);
    final_kernel<<<1, 64, 0, stream>>>(blocksum, out);
}